// Round 4
// baseline (145.562 us; speedup 1.0000x reference)
//
#include <hip/hip_runtime.h>

typedef unsigned short u16;
typedef __attribute__((ext_vector_type(4))) float f32x4;
typedef __attribute__((ext_vector_type(8))) short short8;
typedef __attribute__((ext_vector_type(8))) __bf16 bf16x8;

// round-to-nearest-even f32 -> bf16 bits
__device__ __forceinline__ u16 f2bf(float f) {
  unsigned u = __builtin_bit_cast(unsigned, f);
  u = u + 0x7fffu + ((u >> 16) & 1u);
  return (u16)(u >> 16);
}

// async global->LDS, 16B per lane. LDS dest must be wave-uniform base (+lane*16 implicit).
__device__ __forceinline__ void load_lds16(const void* g, void* l) {
  __builtin_amdgcn_global_load_lds((__attribute__((address_space(1))) void*)g,
                                   (__attribute__((address_space(3))) void*)l,
                                   16, 0, 0);
}

__global__ __launch_bounds__(256) void cast_f32_bf16(const float* __restrict__ in,
                                                     u16* __restrict__ out, int n4) {
  int i = blockIdx.x * 256 + threadIdx.x;
  if (i >= n4) return;
  const float4 v = ((const float4*)in)[i];
  ushort4 o;
  o.x = f2bf(v.x); o.y = f2bf(v.y); o.z = f2bf(v.z); o.w = f2bf(v.w);
  ((ushort4*)out)[i] = o;
}

// per-head inclusive cumsum of weight (f32, matches reference normalizer)
__global__ __launch_bounds__(256) void cumsum_rows(const float* __restrict__ w,
                                                   float* __restrict__ norm) {
  const int h = blockIdx.x, tid = threadIdx.x;
  __shared__ float ts[256];
  float v[8];
  const float* src = w + h * 2048 + tid * 8;
  float s = 0.f;
#pragma unroll
  for (int j = 0; j < 8; ++j) v[j] = src[j];
#pragma unroll
  for (int j = 0; j < 8; ++j) { s += v[j]; v[j] = s; }
  ts[tid] = s;
  __syncthreads();
  float x = s;
#pragma unroll
  for (int d = 1; d < 256; d <<= 1) {
    float y = (tid >= d) ? ts[tid - d] : 0.f;
    __syncthreads();
    x += y;
    ts[tid] = x;
    __syncthreads();
  }
  const float excl = x - s;
  float* dst = norm + h * 2048 + tid * 8;
#pragma unroll
  for (int j = 0; j < 8; ++j) dst[j] = excl + v[j];
}

// NT GEMM: A [M][K] bf16 row-major, B [N][K] bf16 row-major, C[M][N].
// 128x128 tile, BK=32, 4 waves (2x2), 4x4 16x16x32 fragments per wave (m97 structure).
template <bool BIAS, bool F32OUT>
__global__ __launch_bounds__(256) void gemm_nt(const u16* __restrict__ A,
                                               const u16* __restrict__ B,
                                               void* __restrict__ C,
                                               const float* __restrict__ bias,
                                               int M, int N, int K,
                                               int lda, int ldb, int ldc) {
  (void)M; (void)N;
  __shared__ __align__(16) u16 As[128 * 32];
  __shared__ __align__(16) u16 Bs[128 * 32];
  const int tid = threadIdx.x;
  const int lane = tid & 63;
  const int wv = tid >> 6;
  const int wm = wv >> 1, wn = wv & 1;
  const int m0 = blockIdx.y * 128, n0 = blockIdx.x * 128;
  const int l15 = lane & 15, g = lane >> 4;

  f32x4 acc[4][4] = {};

  for (int kt = 0; kt < K; kt += 32) {
    __syncthreads();
#pragma unroll
    for (int i = 0; i < 2; ++i) {
      const int off = tid * 8 + i * 2048;   // element offset in the 128x32 tile
      const int row = off >> 5, col = off & 31;
      load_lds16(A + (size_t)(m0 + row) * lda + kt + col, As + i * 2048 + wv * 512);
      load_lds16(B + (size_t)(n0 + row) * ldb + kt + col, Bs + i * 2048 + wv * 512);
    }
    __syncthreads();   // compiler drains vmcnt before s_barrier
    bf16x8 af[4], bf[4];
#pragma unroll
    for (int mf = 0; mf < 4; ++mf)
      af[mf] = *(const bf16x8*)(As + (wm * 64 + mf * 16 + l15) * 32 + g * 8);
#pragma unroll
    for (int nf = 0; nf < 4; ++nf)
      bf[nf] = *(const bf16x8*)(Bs + (wn * 64 + nf * 16 + l15) * 32 + g * 8);
#pragma unroll
    for (int mf = 0; mf < 4; ++mf)
#pragma unroll
      for (int nf = 0; nf < 4; ++nf)
        acc[mf][nf] = __builtin_amdgcn_mfma_f32_16x16x32_bf16(af[mf], bf[nf],
                                                              acc[mf][nf], 0, 0, 0);
  }

  // D layout (m89-verified): col = lane&15, row = (lane>>4)*4 + reg
#pragma unroll
  for (int mf = 0; mf < 4; ++mf) {
#pragma unroll
    for (int r = 0; r < 4; ++r) {
      const int row = m0 + wm * 64 + mf * 16 + g * 4 + r;
      const float bb = BIAS ? bias[row] : 0.f;
#pragma unroll
      for (int nf = 0; nf < 4; ++nf) {
        const int col = n0 + wn * 64 + nf * 16 + l15;
        const float v = acc[mf][nf][r] + bb;
        if (F32OUT)
          ((float*)C)[(size_t)row * ldc + col] = v;
        else
          ((u16*)C)[(size_t)row * ldc + col] = f2bf(v);
      }
    }
  }
}

// Causal Toeplitz conv per (b, h, t-tile of 128):
//   Yt[t][d] = sum_{s<=t} w[h,t-s] * X1t[h*64+d][b*2048+s]
// A-operand = Toeplitz fragments from LDS w-row (masked o>=0),
// B-operand = X tile [64 d][128 s] staged with XOR-chunk swizzle (16B chunks).
__global__ __launch_bounds__(256) void toep_conv(const u16* __restrict__ X1t,
                                                 const u16* __restrict__ wrow,
                                                 const float* __restrict__ normB,
                                                 const float* __restrict__ biasB,
                                                 u16* __restrict__ Y2b) {
  __shared__ __align__(16) u16 Xs[64 * 128];
  __shared__ __align__(16) u16 wl[2048];
  const int tid = threadIdx.x;
  const int lane = tid & 63, wv = tid >> 6;
  const int tt = 15 - (int)blockIdx.x;   // heavy tiles dispatched first
  const int h = blockIdx.y, b = blockIdx.z;
  const int t0 = tt * 128;
  const int l15 = lane & 15, g = lane >> 4;

  // whole w-row for this head into LDS (4KB)
  ((uint4*)wl)[tid] = ((const uint4*)(wrow + h * 2048))[tid];

  f32x4 acc[2][4] = {};
  const int nst = tt + 1;
  for (int st = 0; st < nst; ++st) {
    const int s0 = st * 128;
    __syncthreads();
#pragma unroll
    for (int i = 0; i < 4; ++i) {
      const int t2 = tid + i * 256;
      const int row = t2 >> 4;                       // d-row 0..63
      const int c8 = (t2 & 15) ^ (row & 15);         // inverse-swizzled source chunk
      load_lds16(X1t + (size_t)(h * 64 + row) * 8192 + b * 2048 + s0 + c8 * 8,
                 Xs + i * 2048 + wv * 512);
    }
    __syncthreads();
#pragma unroll
    for (int ks = 0; ks < 4; ++ks) {
      bf16x8 af[2];
#pragma unroll
      for (int tf = 0; tf < 2; ++tf) {
        const int trow = t0 + wv * 32 + tf * 16 + l15;
        const int sb = s0 + ks * 32 + g * 8;
        short8 av;
#pragma unroll
        for (int j = 0; j < 8; ++j) {
          const int o = trow - (sb + j);
          const int oc = o < 0 ? 0 : o;
          const u16 wbits = wl[oc];
          av[j] = (o < 0) ? (short)0 : (short)wbits;
        }
        af[tf] = __builtin_bit_cast(bf16x8, av);
      }
#pragma unroll
      for (int nf = 0; nf < 4; ++nf) {
        const int row = nf * 16 + l15;
        const int slot = (ks * 4 + g) ^ (row & 15);  // swizzled read chunk
        const bf16x8 bv = *(const bf16x8*)(Xs + row * 128 + slot * 8);
#pragma unroll
        for (int tf = 0; tf < 2; ++tf)
          acc[tf][nf] = __builtin_amdgcn_mfma_f32_16x16x32_bf16(af[tf], bv,
                                                                acc[tf][nf], 0, 0, 0);
      }
    }
  }

#pragma unroll
  for (int tf = 0; tf < 2; ++tf) {
#pragma unroll
    for (int r = 0; r < 4; ++r) {
      const int t = t0 + wv * 32 + tf * 16 + g * 4 + r;
      const float inv = 1.0f / normB[h * 2048 + t];
      const float bb = biasB[h * 2048 + t];
#pragma unroll
      for (int nf = 0; nf < 4; ++nf) {
        const int d = nf * 16 + l15;
        const float v = acc[tf][nf][r] * inv + bb;
        Y2b[(size_t)(b * 2048 + t) * 1024 + h * 64 + d] = f2bf(v);
      }
    }
  }
}

extern "C" void kernel_launch(void* const* d_in, const int* in_sizes, int n_in,
                              void* d_out, int out_size, void* d_ws, size_t ws_size,
                              hipStream_t stream) {
  (void)in_sizes; (void)n_in; (void)out_size; (void)ws_size;
  const float* x      = (const float*)d_in[0];
  const float* weight = (const float*)d_in[1];
  const float* biasB  = (const float*)d_in[2];
  const float* inp_w  = (const float*)d_in[3];
  const float* inp_b  = (const float*)d_in[4];
  const float* out_w  = (const float*)d_in[5];

  char* ws = (char*)d_ws;
  u16* Xb    = (u16*)(ws + 0);                         // x bf16        16 MB
  u16* X1t   = (u16*)(ws + (size_t)(16u << 20));       // x1 transposed 16 MB [1024][8192]
  u16* Y2b   = (u16*)(ws + (size_t)(32u << 20));       // conv out      16 MB [8192][1024]
  u16* Wb    = (u16*)(ws + (size_t)(48u << 20));       // inp_w bf16     2 MB
  u16* OWb   = (u16*)(ws + (size_t)(50u << 20));       // out_w bf16     2 MB
  u16* wbv   = (u16*)(ws + (size_t)(52u << 20));       // weight bf16   64 KB
  float* normB = (float*)(ws + (size_t)(53u << 20));   // cumsum       128 KB

  cast_f32_bf16<<<8192, 256, 0, stream>>>(x, Xb, 2097152);
  cast_f32_bf16<<<1024, 256, 0, stream>>>(inp_w, Wb, 262144);
  cast_f32_bf16<<<1024, 256, 0, stream>>>(out_w, OWb, 262144);
  cast_f32_bf16<<<32, 256, 0, stream>>>(weight, wbv, 8192);
  cumsum_rows<<<16, 256, 0, stream>>>(weight, normB);

  // X1t[e][n] = sum_k inp_w[e,k]*x[n,k] + inp_b[e]   (n = b*2048+s)
  gemm_nt<true, false><<<dim3(64, 8), 256, 0, stream>>>(
      Wb, Xb, (void*)X1t, inp_b, 1024, 8192, 1024, 1024, 1024, 8192);

  // Y2b[(b,t)][h*64+d] = (sum_{s<=t} w[h,t-s]*X1t[h*64+d][b*2048+s]) / norm[h,t] + bias[h,t]
  toep_conv<<<dim3(16, 16, 4), 256, 0, stream>>>(X1t, wbv, normB, biasB, Y2b);

  // out[(b,t)][e'] = sum_e Y2b[(b,t)][e] * out_w[e',e]
  gemm_nt<false, true><<<dim3(8, 64), 256, 0, stream>>>(
      Y2b, OWb, d_out, nullptr, 8192, 1024, 1024, 1024, 1024, 1024);
}